// Round 1
// baseline (54.234 us; speedup 1.0000x reference)
//
#include <hip/hip_runtime.h>

// DeepPoly affine transformer, fused single-pass over weight.
// weight: [4096, 8192] f32 (128 MiB, the only big input -> memory bound)
// out:    [2, 4096] f32  (row 0 = lower, row 1 = upper)

constexpr int N_OUT = 4096;
constexpr int N_IN  = 8192;
constexpr int BLK   = 256;   // threads per block (4 waves)
constexpr int ROWS  = 4;     // output rows per block
constexpr int KITER = N_IN / 4 / BLK;  // 8 float4 chunks per thread

__device__ __forceinline__ float4 ld4(const float* p) {
    return *reinterpret_cast<const float4*>(p);
}

__device__ __forceinline__ float waveRed(float v) {
#pragma unroll
    for (int off = 32; off > 0; off >>= 1)
        v += __shfl_xor(v, off, 64);
    return v;
}

__global__ __launch_bounds__(BLK) void deeppoly_kernel(
        const float* __restrict__ W,
        const float* __restrict__ bias,
        const float* __restrict__ bounds,   // [2, N_IN] : l, u
        const float* __restrict__ bounds0,  // [2, N_IN] : l0, u0
        const float* __restrict__ beta,
        const float* __restrict__ lmbda,
        const float* __restrict__ mu,
        float* __restrict__ out)            // [2, N_OUT]
{
    const int b  = blockIdx.x;
    const int t  = threadIdx.x;
    const int r0 = b * ROWS;

    const float* lo  = bounds;
    const float* up  = bounds + N_IN;
    const float* lo0 = bounds0;
    const float* up0 = bounds0 + N_IN;

    float accL[ROWS]  = {0.f, 0.f, 0.f, 0.f};
    float accU[ROWS]  = {0.f, 0.f, 0.f, 0.f};
    float accMl[ROWS] = {0.f, 0.f, 0.f, 0.f};
    float accMu[ROWS] = {0.f, 0.f, 0.f, 0.f};
    float accBl[ROWS] = {0.f, 0.f, 0.f, 0.f};
    float accBu[ROWS] = {0.f, 0.f, 0.f, 0.f};

#pragma unroll
    for (int k = 0; k < KITER; ++k) {
        const int c = (t + k * BLK) * 4;  // starting float index of this chunk

        const float4 lv  = ld4(lo  + c);
        const float4 uv  = ld4(up  + c);
        const float4 bev = ld4(beta + c);
        const float4 lav = ld4(lmbda + c);
        const float4 muv = ld4(mu  + c);
        const float4 l0v = ld4(lo0 + c);
        const float4 u0v = ld4(up0 + c);

        // A = beta*l0 (used when the effective M coefficient is >=0 on the
        // lower path / <0 on the upper path); B = lmbda*u0 (the mirror).
        const float Ax = bev.x * l0v.x, Ay = bev.y * l0v.y,
                    Az = bev.z * l0v.z, Aw = bev.w * l0v.w;
        const float Bx = lav.x * u0v.x, By = lav.y * u0v.y,
                    Bz = lav.z * u0v.z, Bw = lav.w * u0v.w;

#pragma unroll
        for (int r = 0; r < ROWS; ++r) {
            const float4 wv = ld4(W + (size_t)(r0 + r) * N_IN + c);

#define UPD(wc, lc, uc, Ac, Bc, mc)                                  \
            {                                                        \
                const float w_ = (wc);                               \
                const bool pos = (w_ >= 0.f);                        \
                accL[r]  = fmaf(w_, pos ? (lc) : (uc), accL[r]);     \
                accU[r]  = fmaf(w_, pos ? (uc) : (lc), accU[r]);     \
                accMl[r] = fmaf(w_, pos ? (Ac) : (Bc), accMl[r]);    \
                accMu[r] = fmaf(w_, pos ? (Bc) : (Ac), accMu[r]);    \
                accBl[r] = fmaf(fminf(w_, 0.f), (mc), accBl[r]);     \
                accBu[r] = fmaf(fmaxf(w_, 0.f), (mc), accBu[r]);     \
            }

            UPD(wv.x, lv.x, uv.x, Ax, Bx, muv.x)
            UPD(wv.y, lv.y, uv.y, Ay, By, muv.y)
            UPD(wv.z, lv.z, uv.z, Az, Bz, muv.z)
            UPD(wv.w, lv.w, uv.w, Aw, Bw, muv.w)
#undef UPD
        }
    }

    // ---- block reduction: wave shuffle-reduce, then LDS across 4 waves ----
    __shared__ float red[BLK / 64][ROWS][6];
    const int wave = t >> 6;
    const int lane = t & 63;

#pragma unroll
    for (int r = 0; r < ROWS; ++r) {
        const float sL  = waveRed(accL[r]);
        const float sU  = waveRed(accU[r]);
        const float sMl = waveRed(accMl[r]);
        const float sMu = waveRed(accMu[r]);
        const float sBl = waveRed(accBl[r]);
        const float sBu = waveRed(accBu[r]);
        if (lane == 0) {
            red[wave][r][0] = sL;
            red[wave][r][1] = sU;
            red[wave][r][2] = sMl;
            red[wave][r][3] = sMu;
            red[wave][r][4] = sBl;
            red[wave][r][5] = sBu;
        }
    }
    __syncthreads();

    if (t < ROWS) {
        float L = 0.f, U = 0.f, Ml = 0.f, Mu = 0.f, Bl = 0.f, Bu = 0.f;
#pragma unroll
        for (int w = 0; w < BLK / 64; ++w) {
            L  += red[w][t][0];
            U  += red[w][t][1];
            Ml += red[w][t][2];
            Mu += red[w][t][3];
            Bl += red[w][t][4];
            Bu += red[w][t][5];
        }
        const int   i  = r0 + t;
        const float bi = bias[i];

        const float lower     = L + bi;
        const float upper     = U + bi;
        const float new_lower = Ml + bi + Bl;
        const float new_upper = Mu + bi + Bu;

        out[i]         = fmaxf(lower, new_lower);
        out[N_OUT + i] = fminf(upper, new_upper);
    }
}

extern "C" void kernel_launch(void* const* d_in, const int* in_sizes, int n_in,
                              void* d_out, int out_size, void* d_ws, size_t ws_size,
                              hipStream_t stream) {
    const float* W       = (const float*)d_in[0];
    const float* bias    = (const float*)d_in[1];
    const float* bounds  = (const float*)d_in[2];
    const float* bounds0 = (const float*)d_in[3];
    const float* beta    = (const float*)d_in[4];
    const float* lmbda   = (const float*)d_in[5];
    const float* mu      = (const float*)d_in[6];
    float* out = (float*)d_out;

    deeppoly_kernel<<<N_OUT / ROWS, BLK, 0, stream>>>(
        W, bias, bounds, bounds0, beta, lmbda, mu, out);
}

// Round 2
// 40.722 us; speedup vs baseline: 1.3318x; 1.3318x over previous
//
#include <hip/hip_runtime.h>

// DeepPoly affine transformer — fused single pass over weight with the
// interval-arithmetic identity:
//   Wp@x + Wm@y = 0.5*( W@(x+y) - |W|@(y-x) )   [lower-style]
//   Wp@y + Wm@x = 0.5*( W@(x+y) + |W|@(y-x) )   [upper-style]
// and the mu back-substitution folded into the relaxation coefficients:
//   new_lower = bias + sum( wp*A + wm*B ),  A = beta*l0, B = lmbda*u0 + mu
//   new_upper = bias + sum( wp*B + wm*A )
// => per weight element: 1 abs + 4 FMA, on 4 precomputed column vectors.

constexpr int N_OUT = 4096;
constexpr int N_IN  = 8192;
constexpr int BLK   = 256;             // 4 waves
constexpr int ROWS  = 4;               // output rows per block
constexpr int KITER = N_IN / 4 / BLK;  // 8 float4 chunks per thread

__device__ __forceinline__ float4 ld4(const float* p) {
    return *reinterpret_cast<const float4*>(p);
}

__device__ __forceinline__ float waveRed(float v) {
#pragma unroll
    for (int off = 32; off > 0; off >>= 1)
        v += __shfl_xor(v, off, 64);
    return v;
}

// ---- pass 1: build the 4 fused column vectors into workspace ----
__global__ __launch_bounds__(256) void precompute_cols(
        const float* __restrict__ bounds,   // [2, N_IN]
        const float* __restrict__ bounds0,  // [2, N_IN]
        const float* __restrict__ beta,
        const float* __restrict__ lmbda,
        const float* __restrict__ mu,
        float* __restrict__ cols)           // [4, N_IN] in d_ws
{
    const int i = blockIdx.x * 256 + threadIdx.x;
    if (i >= N_IN) return;
    const float l  = bounds[i],  u  = bounds[i + N_IN];
    const float l0 = bounds0[i], u0 = bounds0[i + N_IN];
    const float A  = beta[i] * l0;
    const float B  = fmaf(lmbda[i], u0, mu[i]);
    cols[i]             = l + u;   // s1
    cols[i + N_IN]      = u - l;   // d1  (>= 0)
    cols[i + 2 * N_IN]  = A + B;   // s2
    cols[i + 3 * N_IN]  = B - A;   // d2
}

// ---- pass 2: stream the weight once ----
__global__ __launch_bounds__(BLK) void deeppoly_main(
        const float* __restrict__ W,
        const float* __restrict__ bias,
        const float* __restrict__ cols,
        float* __restrict__ out)            // [2, N_OUT]
{
    const int t  = threadIdx.x;
    const int r0 = blockIdx.x * ROWS;

    const float* s1 = cols;
    const float* d1 = cols + N_IN;
    const float* s2 = cols + 2 * N_IN;
    const float* d2 = cols + 3 * N_IN;

    float aS[ROWS]  = {0.f, 0.f, 0.f, 0.f};
    float aD[ROWS]  = {0.f, 0.f, 0.f, 0.f};
    float aMS[ROWS] = {0.f, 0.f, 0.f, 0.f};
    float aMD[ROWS] = {0.f, 0.f, 0.f, 0.f};

#pragma unroll
    for (int k = 0; k < KITER; ++k) {
        const int c = (t + k * BLK) * 4;

        const float4 s1v = ld4(s1 + c);
        const float4 d1v = ld4(d1 + c);
        const float4 s2v = ld4(s2 + c);
        const float4 d2v = ld4(d2 + c);

#pragma unroll
        for (int r = 0; r < ROWS; ++r) {
            const float4 wv = ld4(W + (size_t)(r0 + r) * N_IN + c);

#define UPD(wc, s1c, d1c, s2c, d2c)                      \
            {                                            \
                const float w_ = (wc);                   \
                const float a_ = fabsf(w_);              \
                aS[r]  = fmaf(w_, (s1c), aS[r]);         \
                aD[r]  = fmaf(a_, (d1c), aD[r]);         \
                aMS[r] = fmaf(w_, (s2c), aMS[r]);        \
                aMD[r] = fmaf(a_, (d2c), aMD[r]);        \
            }
            UPD(wv.x, s1v.x, d1v.x, s2v.x, d2v.x)
            UPD(wv.y, s1v.y, d1v.y, s2v.y, d2v.y)
            UPD(wv.z, s1v.z, d1v.z, s2v.z, d2v.z)
            UPD(wv.w, s1v.w, d1v.w, s2v.w, d2v.w)
#undef UPD
        }
    }

    // ---- block reduction ----
    __shared__ float red[BLK / 64][ROWS][4];
    const int wave = t >> 6;
    const int lane = t & 63;

#pragma unroll
    for (int r = 0; r < ROWS; ++r) {
        const float vS  = waveRed(aS[r]);
        const float vD  = waveRed(aD[r]);
        const float vMS = waveRed(aMS[r]);
        const float vMD = waveRed(aMD[r]);
        if (lane == 0) {
            red[wave][r][0] = vS;
            red[wave][r][1] = vD;
            red[wave][r][2] = vMS;
            red[wave][r][3] = vMD;
        }
    }
    __syncthreads();

    if (t < ROWS) {
        float S = 0.f, D = 0.f, MS = 0.f, MD = 0.f;
#pragma unroll
        for (int w = 0; w < BLK / 64; ++w) {
            S  += red[w][t][0];
            D  += red[w][t][1];
            MS += red[w][t][2];
            MD += red[w][t][3];
        }
        const int   i  = r0 + t;
        const float bi = bias[i];

        const float lower     = fmaf(0.5f, S - D, bi);
        const float upper     = fmaf(0.5f, S + D, bi);
        const float new_lower = fmaf(0.5f, MS - MD, bi);
        const float new_upper = fmaf(0.5f, MS + MD, bi);

        out[i]         = fmaxf(lower, new_lower);
        out[N_OUT + i] = fminf(upper, new_upper);
    }
}

extern "C" void kernel_launch(void* const* d_in, const int* in_sizes, int n_in,
                              void* d_out, int out_size, void* d_ws, size_t ws_size,
                              hipStream_t stream) {
    const float* W       = (const float*)d_in[0];
    const float* bias    = (const float*)d_in[1];
    const float* bounds  = (const float*)d_in[2];
    const float* bounds0 = (const float*)d_in[3];
    const float* beta    = (const float*)d_in[4];
    const float* lmbda   = (const float*)d_in[5];
    const float* mu      = (const float*)d_in[6];
    float* out  = (float*)d_out;
    float* cols = (float*)d_ws;   // 4 * N_IN floats = 128 KB

    precompute_cols<<<N_IN / 256, 256, 0, stream>>>(
        bounds, bounds0, beta, lmbda, mu, cols);
    deeppoly_main<<<N_OUT / ROWS, BLK, 0, stream>>>(W, bias, cols, out);
}